// Round 1
// baseline (7407.536 us; speedup 1.0000x reference)
//
#include <hip/hip_runtime.h>

#define NQT 16384
#define NAT 512
#define EAQ 131072
#define EQQ 262144

__device__ __forceinline__ float silu_f(float x){ return x / (1.f + __expf(-x)); }

// ---------------- h_atom = atom_feat @ W + b : (512,256)@(256,128) ----------------
__global__ __launch_bounds__(128) void k_hatom(
    const float* __restrict__ feat, const float* __restrict__ W,
    const float* __restrict__ b, float* __restrict__ out)
{
  __shared__ float sf[256];
  int n = blockIdx.x, t = threadIdx.x;
  sf[t]       = feat[n*256 + t];
  sf[t + 128] = feat[n*256 + 128 + t];
  __syncthreads();
  float acc = b[t];
  for (int k = 0; k < 256; k++) acc += sf[k] * W[k*128 + t];
  out[n*128 + t] = acc;
}

// ---------------- t_emb : sinusoid -> (N,128)@(128,512) silu @(512,128) ----------------
__global__ __launch_bounds__(256) void k_temb(
    const float* __restrict__ tq,
    const float* __restrict__ W1, const float* __restrict__ b1,
    const float* __restrict__ W2, const float* __restrict__ b2,
    float* __restrict__ temb)
{
  __shared__ float emb[128*8];   // [k][n], stride 8
  __shared__ float hid[512*8];   // [k][n], stride 8
  int t = threadIdx.x, n0 = blockIdx.x * 8;
  #pragma unroll
  for (int i = 0; i < 4; i++){
    int idx = t + 256*i;
    int k = idx >> 3, n = idx & 7;
    float tv = tq[n0 + n];
    int h = k & 63;
    float freq = __expf(-9.210340371976184f * (float)h * (1.f/63.f));
    float a = tv * freq;
    emb[idx] = (k < 64) ? __sinf(a) : __cosf(a);
  }
  __syncthreads();
  float acc[16];
  #pragma unroll
  for (int i = 0; i < 16; i++) acc[i] = 0.f;
  const float4* ev = (const float4*)emb;
  for (int k = 0; k < 128; k++){
    float wa = W1[k*512 + t];
    float wb = W1[k*512 + t + 256];
    float4 e0 = ev[k*2], e1 = ev[k*2 + 1];
    acc[0]+=wa*e0.x; acc[1]+=wa*e0.y; acc[2]+=wa*e0.z; acc[3]+=wa*e0.w;
    acc[4]+=wa*e1.x; acc[5]+=wa*e1.y; acc[6]+=wa*e1.z; acc[7]+=wa*e1.w;
    acc[8]+=wb*e0.x; acc[9]+=wb*e0.y; acc[10]+=wb*e0.z; acc[11]+=wb*e0.w;
    acc[12]+=wb*e1.x; acc[13]+=wb*e1.y; acc[14]+=wb*e1.z; acc[15]+=wb*e1.w;
  }
  float ba = b1[t], bb = b1[t + 256];
  #pragma unroll
  for (int n = 0; n < 8; n++){
    hid[t*8 + n]        = silu_f(acc[n] + ba);
    hid[(t+256)*8 + n]  = silu_f(acc[8+n] + bb);
  }
  __syncthreads();
  float a2[4] = {0.f,0.f,0.f,0.f};
  int c = t & 127, nh = t >> 7;
  const float4* hv = (const float4*)hid;
  for (int k = 0; k < 512; k++){
    float w = W2[k*128 + c];
    float4 h4 = hv[k*2 + nh];
    a2[0]+=w*h4.x; a2[1]+=w*h4.y; a2[2]+=w*h4.z; a2[3]+=w*h4.w;
  }
  float bc = b2[c];
  #pragma unroll
  for (int i = 0; i < 4; i++)
    temb[(size_t)(n0 + nh*4 + i)*128 + c] = a2[i] + bc;
}

// ---------------- h init: mean-dist feature -> tiny MLP ----------------
__global__ __launch_bounds__(128) void k_hinit(
    const float* __restrict__ x_t, const float* __restrict__ atom_pos,
    const float* __restrict__ W1, const float* __restrict__ b1,
    const float* __restrict__ W2, const float* __restrict__ b2,
    float* __restrict__ h)
{
  __shared__ float sh[128];
  __shared__ float sld;
  int n = blockIdx.x, t = threadIdx.x;
  float qx = x_t[n*3], qy = x_t[n*3+1], qz = x_t[n*3+2];
  float part = 0.f;
  if (t < 64){
    int a = (n >> 11)*64 + t;     // batch = n / 2048, 64 atoms per batch
    float dx = qx - atom_pos[a*3];
    float dy = qy - atom_pos[a*3+1];
    float dz = qz - atom_pos[a*3+2];
    part = dx*dx + dy*dy + dz*dz;
  }
  #pragma unroll
  for (int off = 32; off; off >>= 1) part += __shfl_down(part, off);
  if (t == 0) sld = log1pf(sqrtf(part * (1.f/64.f)) * 0.125f);
  __syncthreads();
  float ld = sld;
  sh[t] = silu_f(ld * W1[t] + b1[t]);
  __syncthreads();
  float acc = b2[t];
  for (int k = 0; k < 128; k++) acc += sh[k] * W2[k*128 + t];
  h[(size_t)n*128 + t] = acc;
}

// ---------------- EGNN edge kernel: 16 edges / 256-thread block ----------------
__global__ __launch_bounds__(256) void k_edge(
    const float* __restrict__ h_src, const float* __restrict__ h_tgt,
    const float* __restrict__ pos_src, const float* __restrict__ pos_tgt,
    const float* __restrict__ temb,
    const int* __restrict__ esrc, const int* __restrict__ etgt,
    const float* __restrict__ W1, const float* __restrict__ b1,   // (385,256)
    const float* __restrict__ W2, const float* __restrict__ b2,   // (256,128)
    const float* __restrict__ W3, const float* __restrict__ b3,   // (128,64)
    const float* __restrict__ W4, const float* __restrict__ b4,   // (64,1)
    float* __restrict__ agg, float* __restrict__ vel)
{
  __shared__ float mi[385*16];    // [k][e] stride 16; reused as h3 [64][16] later
  __shared__ float hid[256*16];
  __shared__ float msg[128*16];
  __shared__ float srel[16*3];
  __shared__ int   stgt[16];

  int t = threadIdx.x;
  int e0 = blockIdx.x * 16;

  { // stage mi transposed: 16 threads per edge
    int l = t & 15, e = t >> 4;
    int src = esrc[e0 + e], tgt = etgt[e0 + e];
    float rx = pos_tgt[tgt*3+0] - pos_src[src*3+0];
    float ry = pos_tgt[tgt*3+1] - pos_src[src*3+1];
    float rz = pos_tgt[tgt*3+2] - pos_src[src*3+2];
    const float* hs = h_src + (size_t)src*128;
    const float* ht = h_tgt + (size_t)tgt*128;
    const float* te = temb  + (size_t)tgt*128;
    #pragma unroll
    for (int i = 0; i < 8; i++){
      int k = l + 16*i;
      mi[k*16 + e]         = hs[k];
      mi[(128 + k)*16 + e] = ht[k];
      mi[(257 + k)*16 + e] = te[k];
    }
    if (l == 0){
      mi[256*16 + e] = rx*rx + ry*ry + rz*rz;
      stgt[e] = tgt;
      srel[e*3+0] = rx; srel[e*3+1] = ry; srel[e*3+2] = rz;
    }
  }
  __syncthreads();

  { // GEMM1: (16 x 385)@(385 x 256) + silu -> hid
    int j = t & 127, eh = t >> 7;
    float acc[16];
    #pragma unroll
    for (int i = 0; i < 16; i++) acc[i] = 0.f;
    const float4* mv = (const float4*)mi;
    for (int k = 0; k < 385; k++){
      float wa = W1[k*256 + j];
      float wb = W1[k*256 + j + 128];
      float4 m0 = mv[k*4 + eh*2];
      float4 m1 = mv[k*4 + eh*2 + 1];
      acc[0]+=wa*m0.x; acc[1]+=wa*m0.y; acc[2]+=wa*m0.z; acc[3]+=wa*m0.w;
      acc[4]+=wa*m1.x; acc[5]+=wa*m1.y; acc[6]+=wa*m1.z; acc[7]+=wa*m1.w;
      acc[8]+=wb*m0.x; acc[9]+=wb*m0.y; acc[10]+=wb*m0.z; acc[11]+=wb*m0.w;
      acc[12]+=wb*m1.x; acc[13]+=wb*m1.y; acc[14]+=wb*m1.z; acc[15]+=wb*m1.w;
    }
    float ba = b1[j], bb = b1[j + 128];
    #pragma unroll
    for (int i = 0; i < 8; i++){
      int e = eh*8 + i;
      hid[j*16 + e]         = silu_f(acc[i] + ba);
      hid[(j + 128)*16 + e] = silu_f(acc[8+i] + bb);
    }
  }
  __syncthreads();

  int c2 = t & 63, eq = t >> 6;
  { // GEMM2: (16 x 256)@(256 x 128) + silu -> msg, scatter agg
    float acc[8];
    #pragma unroll
    for (int i = 0; i < 8; i++) acc[i] = 0.f;
    const float4* hv = (const float4*)hid;
    for (int k = 0; k < 256; k++){
      float wa = W2[k*128 + c2];
      float wb = W2[k*128 + c2 + 64];
      float4 h4 = hv[k*4 + eq];
      acc[0]+=wa*h4.x; acc[1]+=wa*h4.y; acc[2]+=wa*h4.z; acc[3]+=wa*h4.w;
      acc[4]+=wb*h4.x; acc[5]+=wb*h4.y; acc[6]+=wb*h4.z; acc[7]+=wb*h4.w;
    }
    float ba = b2[c2], bb = b2[c2 + 64];
    #pragma unroll
    for (int i = 0; i < 4; i++){
      int e = eq*4 + i;
      float v0 = silu_f(acc[i] + ba);
      float v1 = silu_f(acc[4+i] + bb);
      msg[c2*16 + e]        = v0;
      msg[(c2 + 64)*16 + e] = v1;
      int tg = stgt[e];
      atomicAdd(&agg[(size_t)tg*128 + c2], v0);
      atomicAdd(&agg[(size_t)tg*128 + c2 + 64], v1);
    }
  }
  __syncthreads();

  { // GEMM3: (16 x 128)@(128 x 64) + silu -> h3 (aliases mi)
    int c = t & 31, eo = t >> 5;
    float acc[4] = {0.f,0.f,0.f,0.f};
    const float2* mgv = (const float2*)msg;
    for (int k = 0; k < 128; k++){
      float wa = W3[k*64 + c];
      float wb = W3[k*64 + c + 32];
      float2 m2 = mgv[k*8 + eo];
      acc[0]+=wa*m2.x; acc[1]+=wa*m2.y;
      acc[2]+=wb*m2.x; acc[3]+=wb*m2.y;
    }
    float* h3 = mi;
    float ba = b3[c], bb = b3[c + 32];
    h3[c*16 + eo*2]          = silu_f(acc[0] + ba);
    h3[c*16 + eo*2 + 1]      = silu_f(acc[1] + ba);
    h3[(c+32)*16 + eo*2]     = silu_f(acc[2] + bb);
    h3[(c+32)*16 + eo*2 + 1] = silu_f(acc[3] + bb);
  }
  __syncthreads();

  if (t < 16){ // GEMM4 + tanh + vel scatter
    const float* h3 = mi;
    float acc = 0.f;
    for (int k = 0; k < 64; k++) acc += h3[k*16 + t] * W4[k];
    float w = tanhf(acc + b4[0]);
    int tg = stgt[t];
    atomicAdd(&vel[tg*3+0], w * srel[t*3+0]);
    atomicAdd(&vel[tg*3+1], w * srel[t*3+1]);
    atomicAdd(&vel[tg*3+2], w * srel[t*3+2]);
  }
}

// ---------------- node update: u=[h,agg] -> MLP -> residual -> LN ----------------
__global__ __launch_bounds__(256) void k_node(
    const float* __restrict__ h, const float* __restrict__ agg,
    const float* __restrict__ W1, const float* __restrict__ b1,  // (256,128)
    const float* __restrict__ W2, const float* __restrict__ b2,  // (128,128)
    const float* __restrict__ g, const float* __restrict__ bb_,
    float* __restrict__ h_out)
{
  __shared__ float u[256*16];    // [k][n] stride 16
  __shared__ float hid[128*16];
  __shared__ float r[16*128];    // [n][c]
  int t = threadIdx.x;
  int n0 = blockIdx.x * 16;
  {
    int l = t & 15, n = t >> 4;
    const float* hr = h   + (size_t)(n0+n)*128;
    const float* ar = agg + (size_t)(n0+n)*128;
    #pragma unroll
    for (int i = 0; i < 8; i++){
      int k = l + 16*i;
      u[k*16 + n]         = hr[k];
      u[(128 + k)*16 + n] = ar[k];
    }
  }
  __syncthreads();
  int c = t & 63, q = t >> 6;
  {
    float acc[8];
    #pragma unroll
    for (int i = 0; i < 8; i++) acc[i] = 0.f;
    const float4* uv = (const float4*)u;
    for (int k = 0; k < 256; k++){
      float wa = W1[k*128 + c];
      float wb = W1[k*128 + c + 64];
      float4 u4 = uv[k*4 + q];
      acc[0]+=wa*u4.x; acc[1]+=wa*u4.y; acc[2]+=wa*u4.z; acc[3]+=wa*u4.w;
      acc[4]+=wb*u4.x; acc[5]+=wb*u4.y; acc[6]+=wb*u4.z; acc[7]+=wb*u4.w;
    }
    float ba = b1[c], bv = b1[c + 64];
    #pragma unroll
    for (int i = 0; i < 4; i++){
      int n = q*4 + i;
      hid[c*16 + n]        = silu_f(acc[i] + ba);
      hid[(c+64)*16 + n]   = silu_f(acc[4+i] + bv);
    }
  }
  __syncthreads();
  {
    float acc[8];
    #pragma unroll
    for (int i = 0; i < 8; i++) acc[i] = 0.f;
    const float4* hv = (const float4*)hid;
    for (int k = 0; k < 128; k++){
      float wa = W2[k*128 + c];
      float wb = W2[k*128 + c + 64];
      float4 h4 = hv[k*4 + q];
      acc[0]+=wa*h4.x; acc[1]+=wa*h4.y; acc[2]+=wa*h4.z; acc[3]+=wa*h4.w;
      acc[4]+=wb*h4.x; acc[5]+=wb*h4.y; acc[6]+=wb*h4.z; acc[7]+=wb*h4.w;
    }
    float ba = b2[c], bv = b2[c + 64];
    #pragma unroll
    for (int i = 0; i < 4; i++){
      int n = q*4 + i;
      r[n*128 + c]      = h[(size_t)(n0+n)*128 + c]      + acc[i]   + ba;
      r[n*128 + c + 64] = h[(size_t)(n0+n)*128 + c + 64] + acc[4+i] + bv;
    }
  }
  __syncthreads();
  {
    int lane = t & 63, wid = t >> 6;
    #pragma unroll
    for (int nn = 0; nn < 4; nn++){
      int n = wid*4 + nn;
      float a = r[n*128 + lane], b2v = r[n*128 + lane + 64];
      float s = a + b2v, ss = a*a + b2v*b2v;
      #pragma unroll
      for (int off = 1; off < 64; off <<= 1){
        s  += __shfl_xor(s, off);
        ss += __shfl_xor(ss, off);
      }
      float mean = s * (1.f/128.f);
      float var  = ss * (1.f/128.f) - mean*mean;
      float rstd = rsqrtf(var + 1e-5f);
      float* ho = h_out + (size_t)(n0+n)*128;
      ho[lane]      = (a   - mean)*rstd*g[lane]      + bb_[lane];
      ho[lane + 64] = (b2v - mean)*rstd*g[lane + 64] + bb_[lane + 64];
    }
  }
}

// ---------------- output: scale = MLP(h); out = vel*scale ----------------
__global__ __launch_bounds__(128) void k_out(
    const float* __restrict__ h, const float* __restrict__ vel,
    const float* __restrict__ W1, const float* __restrict__ b1,
    const float* __restrict__ W2, const float* __restrict__ b2,
    float* __restrict__ out)
{
  __shared__ float sh[128];
  __shared__ float spart[2];
  int n = blockIdx.x, t = threadIdx.x;
  sh[t] = h[(size_t)n*128 + t];
  __syncthreads();
  float acc = b1[t];
  for (int k = 0; k < 128; k++) acc += sh[k] * W1[k*128 + t];
  float p = silu_f(acc) * W2[t];
  #pragma unroll
  for (int off = 32; off; off >>= 1) p += __shfl_down(p, off);
  if ((t & 63) == 0) spart[t >> 6] = p;
  __syncthreads();
  if (t < 3){
    float scale = spart[0] + spart[1] + b2[0];
    out[n*3 + t] = vel[n*3 + t] * scale;
  }
}

extern "C" void kernel_launch(void* const* d_in, const int* in_sizes, int n_in,
                              void* d_out, int out_size, void* d_ws, size_t ws_size,
                              hipStream_t stream)
{
  const float* x_t       = (const float*)d_in[0];
  const float* t_query   = (const float*)d_in[1];
  const float* atom_pos  = (const float*)d_in[2];
  const float* atom_feat = (const float*)d_in[3];
  const int*   e_aq_s = (const int*)d_in[4];
  const int*   e_aq_t = (const int*)d_in[5];
  const int*   e_qq_s = (const int*)d_in[6];
  const int*   e_qq_t = (const int*)d_in[7];
  const float* apW  = (const float*)d_in[8];
  const float* apb  = (const float*)d_in[9];
  const float* tW1  = (const float*)d_in[10];
  const float* tb1  = (const float*)d_in[11];
  const float* tW2  = (const float*)d_in[12];
  const float* tb2  = (const float*)d_in[13];
  const float* qiW1 = (const float*)d_in[14];
  const float* qib1 = (const float*)d_in[15];
  const float* qiW2 = (const float*)d_in[16];
  const float* qib2 = (const float*)d_in[17];
  const float* mW1  = (const float*)d_in[18];
  const float* mb1  = (const float*)d_in[19];
  const float* mW2  = (const float*)d_in[20];
  const float* mb2  = (const float*)d_in[21];
  const float* cW1  = (const float*)d_in[22];
  const float* cb1  = (const float*)d_in[23];
  const float* cW2  = (const float*)d_in[24];
  const float* cb2  = (const float*)d_in[25];
  const float* nW1  = (const float*)d_in[26];
  const float* nb1  = (const float*)d_in[27];
  const float* nW2  = (const float*)d_in[28];
  const float* nb2  = (const float*)d_in[29];
  const float* lng  = (const float*)d_in[30];
  const float* lnb  = (const float*)d_in[31];
  const float* voW1 = (const float*)d_in[32];
  const float* vob1 = (const float*)d_in[33];
  const float* voW2 = (const float*)d_in[34];
  const float* vob2 = (const float*)d_in[35];
  float* out = (float*)d_out;

  float* ws     = (float*)d_ws;
  float* h_atom = ws;                    // 512*128     = 65536
  float* temb   = h_atom + 65536;        // 16384*128   = 2097152
  float* hA     = temb + 2097152;
  float* hB     = hA + 2097152;
  float* agg    = hB + 2097152;
  float* vel    = agg + 2097152;         // 16384*3     = 49152

  hipMemsetAsync(vel, 0, (size_t)NQT*3*sizeof(float), stream);
  k_hatom<<<NAT, 128, 0, stream>>>(atom_feat, apW, apb, h_atom);
  k_temb<<<NQT/8, 256, 0, stream>>>(t_query, tW1, tb1, tW2, tb2, temb);
  k_hinit<<<NQT, 128, 0, stream>>>(x_t, atom_pos, qiW1, qib1, qiW2, qib2, hA);

  float* hc = hA; float* hn = hB;
  for (int i = 0; i < 4; i++){
    for (int half = 0; half < 2; half++){
      int j = 2*i + half;
      const int* es = half ? e_qq_s : e_aq_s;
      const int* et = half ? e_qq_t : e_aq_t;
      int E = half ? EQQ : EAQ;
      const float* hsrc = half ? hc : h_atom;
      const float* psrc = half ? x_t : atom_pos;
      hipMemsetAsync(agg, 0, (size_t)NQT*128*sizeof(float), stream);
      k_edge<<<E/16, 256, 0, stream>>>(hsrc, hc, psrc, x_t, temb, es, et,
          mW1 + (size_t)j*385*256, mb1 + (size_t)j*256,
          mW2 + (size_t)j*256*128, mb2 + (size_t)j*128,
          cW1 + (size_t)j*128*64,  cb1 + (size_t)j*64,
          cW2 + (size_t)j*64,      cb2 + (size_t)j,
          agg, vel);
      k_node<<<NQT/16, 256, 0, stream>>>(hc, agg,
          nW1 + (size_t)j*256*128, nb1 + (size_t)j*128,
          nW2 + (size_t)j*128*128, nb2 + (size_t)j*128,
          lng + (size_t)j*128,     lnb + (size_t)j*128, hn);
      float* tmp = hc; hc = hn; hn = tmp;
    }
  }
  k_out<<<NQT, 128, 0, stream>>>(hc, vel, voW1, vob1, voW2, vob2, out);
}

// Round 2
// 2097.328 us; speedup vs baseline: 3.5319x; 3.5319x over previous
//
#include <hip/hip_runtime.h>

#define NQT 16384
#define NAT 512
#define EAQ 131072
#define EQQ 262144

typedef short short8 __attribute__((ext_vector_type(8)));
typedef short short4v __attribute__((ext_vector_type(4)));
typedef float float4v __attribute__((ext_vector_type(4)));

__device__ __forceinline__ float silu_f(float x){ return x / (1.f + __expf(-x)); }

__device__ __forceinline__ short f2bf(float f){
  union { float f; unsigned u; } v; v.f = f;
  unsigned r = v.u + 0x7fff + ((v.u >> 16) & 1);
  return (short)(r >> 16);
}

// ---------------- weight packer: (rows,cols) f32 -> MFMA B-frag bf16 ----------------
// out layout per layer: [ntiles][ksteps][64 lanes][8], lane supplies B[k=kk*32+(lane>>4)*8+j][n=nt*16+(lane&15)]
__global__ __launch_bounds__(256) void k_pack(
    const float* __restrict__ W, short* __restrict__ out,
    int rows, int cols, int ksteps, int ntiles, int total, int remap256)
{
  int idx = blockIdx.x * 256 + threadIdx.x;
  if (idx >= total) return;
  int l8   = idx & 7;
  int lane = (idx >> 3) & 63;
  int kk   = (idx >> 9) % ksteps;
  int nt   = ((idx >> 9) / ksteps) % ntiles;
  int j    = idx / (512 * ksteps * ntiles);
  int k = kk*32 + (lane >> 4)*8 + l8;
  if (remap256 && k >= 256) k += 1;          // skip sq row (handled in f32 epilogue)
  int n = nt*16 + (lane & 15);
  out[idx] = f2bf(W[(size_t)j*rows*cols + (size_t)k*cols + n]);
}

// ---------------- h_atom = atom_feat @ W + b : (512,256)@(256,128) ----------------
__global__ __launch_bounds__(128) void k_hatom(
    const float* __restrict__ feat, const float* __restrict__ W,
    const float* __restrict__ b, float* __restrict__ out)
{
  __shared__ float sf[256];
  int n = blockIdx.x, t = threadIdx.x;
  sf[t]       = feat[n*256 + t];
  sf[t + 128] = feat[n*256 + 128 + t];
  __syncthreads();
  float acc = b[t];
  for (int k = 0; k < 256; k++) acc += sf[k] * W[k*128 + t];
  out[n*128 + t] = acc;
}

// ---------------- t_emb ----------------
__global__ __launch_bounds__(256) void k_temb(
    const float* __restrict__ tq,
    const float* __restrict__ W1, const float* __restrict__ b1,
    const float* __restrict__ W2, const float* __restrict__ b2,
    float* __restrict__ temb)
{
  __shared__ float emb[128*8];
  __shared__ float hid[512*8];
  int t = threadIdx.x, n0 = blockIdx.x * 8;
  #pragma unroll
  for (int i = 0; i < 4; i++){
    int idx = t + 256*i;
    int k = idx >> 3, n = idx & 7;
    float tv = tq[n0 + n];
    int h = k & 63;
    float freq = __expf(-9.210340371976184f * (float)h * (1.f/63.f));
    float a = tv * freq;
    emb[idx] = (k < 64) ? __sinf(a) : __cosf(a);
  }
  __syncthreads();
  float acc[16];
  #pragma unroll
  for (int i = 0; i < 16; i++) acc[i] = 0.f;
  const float4* ev = (const float4*)emb;
  for (int k = 0; k < 128; k++){
    float wa = W1[k*512 + t];
    float wb = W1[k*512 + t + 256];
    float4 e0 = ev[k*2], e1 = ev[k*2 + 1];
    acc[0]+=wa*e0.x; acc[1]+=wa*e0.y; acc[2]+=wa*e0.z; acc[3]+=wa*e0.w;
    acc[4]+=wa*e1.x; acc[5]+=wa*e1.y; acc[6]+=wa*e1.z; acc[7]+=wa*e1.w;
    acc[8]+=wb*e0.x; acc[9]+=wb*e0.y; acc[10]+=wb*e0.z; acc[11]+=wb*e0.w;
    acc[12]+=wb*e1.x; acc[13]+=wb*e1.y; acc[14]+=wb*e1.z; acc[15]+=wb*e1.w;
  }
  float ba = b1[t], bb = b1[t + 256];
  #pragma unroll
  for (int n = 0; n < 8; n++){
    hid[t*8 + n]        = silu_f(acc[n] + ba);
    hid[(t+256)*8 + n]  = silu_f(acc[8+n] + bb);
  }
  __syncthreads();
  float a2[4] = {0.f,0.f,0.f,0.f};
  int c = t & 127, nh = t >> 7;
  const float4* hv = (const float4*)hid;
  for (int k = 0; k < 512; k++){
    float w = W2[k*128 + c];
    float4 h4 = hv[k*2 + nh];
    a2[0]+=w*h4.x; a2[1]+=w*h4.y; a2[2]+=w*h4.z; a2[3]+=w*h4.w;
  }
  float bc = b2[c];
  #pragma unroll
  for (int i = 0; i < 4; i++)
    temb[(size_t)(n0 + nh*4 + i)*128 + c] = a2[i] + bc;
}

// ---------------- h init ----------------
__global__ __launch_bounds__(128) void k_hinit(
    const float* __restrict__ x_t, const float* __restrict__ atom_pos,
    const float* __restrict__ W1, const float* __restrict__ b1,
    const float* __restrict__ W2, const float* __restrict__ b2,
    float* __restrict__ h)
{
  __shared__ float sh[128];
  __shared__ float sld;
  int n = blockIdx.x, t = threadIdx.x;
  float qx = x_t[n*3], qy = x_t[n*3+1], qz = x_t[n*3+2];
  float part = 0.f;
  if (t < 64){
    int a = (n >> 11)*64 + t;
    float dx = qx - atom_pos[a*3];
    float dy = qy - atom_pos[a*3+1];
    float dz = qz - atom_pos[a*3+2];
    part = dx*dx + dy*dy + dz*dz;
  }
  #pragma unroll
  for (int off = 32; off; off >>= 1) part += __shfl_down(part, off);
  if (t == 0) sld = log1pf(sqrtf(part * (1.f/64.f)) * 0.125f);
  __syncthreads();
  float ld = sld;
  sh[t] = silu_f(ld * W1[t] + b1[t]);
  __syncthreads();
  float acc = b2[t];
  for (int k = 0; k < 128; k++) acc += sh[k] * W2[k*128 + t];
  h[(size_t)n*128 + t] = acc;
}

// ---------------- EGNN edge kernel, MFMA: 32 edges / 256-thread block ----------------
__global__ __launch_bounds__(256) void k_edge(
    const float* __restrict__ h_src, const float* __restrict__ h_tgt,
    const float* __restrict__ pos_src, const float* __restrict__ pos_tgt,
    const float* __restrict__ temb,
    const int* __restrict__ esrc, const int* __restrict__ etgt,
    const short* __restrict__ W1p, const float* __restrict__ w1full, const float* __restrict__ b1,
    const short* __restrict__ W2p, const float* __restrict__ b2,
    const short* __restrict__ W3p, const float* __restrict__ b3,
    const float* __restrict__ W4,  const float* __restrict__ b4,
    float* __restrict__ agg, float* __restrict__ vel)
{
  __shared__ __align__(16) short A1[32*392];   // mi bf16 [e][384], stride 392; later aliased as A3 (msg)
  __shared__ __align__(16) short A2[32*264];   // hid bf16 [e][256], stride 264; later aliased as h3 f32
  __shared__ float sq_s[32];
  __shared__ float rel_s[32*3];
  __shared__ int   tgt_s[32];
  short* A3 = A1;                 // [e][128], stride 136
  float* h3 = (float*)A2;         // [e][64],  stride 68

  int t = threadIdx.x;
  int e0 = blockIdx.x * 32;

  // ---- stage: gather + cast bf16 (8 threads / edge) ----
  {
    int e = t >> 3, l = t & 7;
    int src = esrc[e0 + e], tgt = etgt[e0 + e];
    const float4* hs = (const float4*)(h_src + (size_t)src*128);
    const float4* ht = (const float4*)(h_tgt + (size_t)tgt*128);
    const float4* te = (const float4*)(temb  + (size_t)tgt*128);
    short* row = A1 + e*392;
    #pragma unroll
    for (int i = 0; i < 4; i++){
      int k4 = l + 8*i;
      float4 a = hs[k4], b = ht[k4], c = te[k4];
      short4v s;
      s.x=f2bf(a.x); s.y=f2bf(a.y); s.z=f2bf(a.z); s.w=f2bf(a.w);
      *(short4v*)(row + k4*4) = s;
      s.x=f2bf(b.x); s.y=f2bf(b.y); s.z=f2bf(b.z); s.w=f2bf(b.w);
      *(short4v*)(row + 128 + k4*4) = s;
      s.x=f2bf(c.x); s.y=f2bf(c.y); s.z=f2bf(c.z); s.w=f2bf(c.w);
      *(short4v*)(row + 256 + k4*4) = s;
    }
    if (l == 0){
      float rx = pos_tgt[tgt*3+0] - pos_src[src*3+0];
      float ry = pos_tgt[tgt*3+1] - pos_src[src*3+1];
      float rz = pos_tgt[tgt*3+2] - pos_src[src*3+2];
      sq_s[e] = rx*rx + ry*ry + rz*rz;
      rel_s[e*3+0]=rx; rel_s[e*3+1]=ry; rel_s[e*3+2]=rz;
      tgt_s[e] = tgt;
    }
  }
  __syncthreads();

  int lane = t & 63, w = t >> 6;
  int mrow = lane & 15, quad = lane >> 4;

  // ---- GEMM1: (32x384)@(384x256) [+ sq rank-1 in f32] + silu -> A2 ----
  for (int nti = 0; nti < 4; nti++){
    int nt = w*4 + nti;
    #pragma unroll
    for (int mt = 0; mt < 2; mt++){
      float4v acc = {0.f,0.f,0.f,0.f};
      const short8* Ab = (const short8*)(A1 + (mt*16 + mrow)*392 + quad*8);
      const short8* Bb = (const short8*)(W1p + (size_t)nt*12*512 + lane*8);
      #pragma unroll
      for (int kk = 0; kk < 12; kk++)
        acc = __builtin_amdgcn_mfma_f32_16x16x32_bf16(Ab[kk*4], Bb[kk*64], acc, 0, 0, 0);
      int n = nt*16 + mrow;
      float w1sq = w1full[256*256 + n];   // row 256 of W1 (sq feature)
      float b1n  = b1[n];
      #pragma unroll
      for (int r = 0; r < 4; r++){
        int e = mt*16 + quad*4 + r;
        float v = acc[r] + b1n + sq_s[e]*w1sq;
        A2[e*264 + n] = f2bf(silu_f(v));
      }
    }
  }
  __syncthreads();

  // ---- GEMM2: (32x256)@(256x128) + silu -> msg; scatter agg; -> A3 ----
  for (int nti = 0; nti < 2; nti++){
    int nt = w*2 + nti;
    #pragma unroll
    for (int mt = 0; mt < 2; mt++){
      float4v acc = {0.f,0.f,0.f,0.f};
      const short8* Ab = (const short8*)(A2 + (mt*16 + mrow)*264 + quad*8);
      const short8* Bb = (const short8*)(W2p + (size_t)nt*8*512 + lane*8);
      #pragma unroll
      for (int kk = 0; kk < 8; kk++)
        acc = __builtin_amdgcn_mfma_f32_16x16x32_bf16(Ab[kk*4], Bb[kk*64], acc, 0, 0, 0);
      int n = nt*16 + mrow;
      float b2n = b2[n];
      #pragma unroll
      for (int r = 0; r < 4; r++){
        int e = mt*16 + quad*4 + r;
        float v = silu_f(acc[r] + b2n);
        atomicAdd(&agg[(size_t)tgt_s[e]*128 + n], v);
        A3[e*136 + n] = f2bf(v);
      }
    }
  }
  __syncthreads();

  // ---- GEMM3: (32x128)@(128x64) + silu -> h3 (f32) ----
  {
    int nt = w;
    #pragma unroll
    for (int mt = 0; mt < 2; mt++){
      float4v acc = {0.f,0.f,0.f,0.f};
      const short8* Ab = (const short8*)(A3 + (mt*16 + mrow)*136 + quad*8);
      const short8* Bb = (const short8*)(W3p + (size_t)nt*4*512 + lane*8);
      #pragma unroll
      for (int kk = 0; kk < 4; kk++)
        acc = __builtin_amdgcn_mfma_f32_16x16x32_bf16(Ab[kk*4], Bb[kk*64], acc, 0, 0, 0);
      int n = nt*16 + mrow;
      float b3n = b3[n];
      #pragma unroll
      for (int r = 0; r < 4; r++){
        int e = mt*16 + quad*4 + r;
        h3[e*68 + n] = silu_f(acc[r] + b3n);
      }
    }
  }
  __syncthreads();

  // ---- GEMM4 (f32 dot-64) + tanh + vel scatter ----
  {
    int e = t >> 3, l = t & 7;
    float p = 0.f;
    #pragma unroll
    for (int i = 0; i < 8; i++){
      int k = l + 8*i;
      p += h3[e*68 + k] * W4[k];
    }
    p += __shfl_xor(p, 1);
    p += __shfl_xor(p, 2);
    p += __shfl_xor(p, 4);
    if (l == 0){
      float wv = tanhf(p + b4[0]);
      int tg = tgt_s[e];
      atomicAdd(&vel[tg*3+0], wv*rel_s[e*3+0]);
      atomicAdd(&vel[tg*3+1], wv*rel_s[e*3+1]);
      atomicAdd(&vel[tg*3+2], wv*rel_s[e*3+2]);
    }
  }
}

// ---------------- node update ----------------
__global__ __launch_bounds__(256) void k_node(
    const float* __restrict__ h, const float* __restrict__ agg,
    const float* __restrict__ W1, const float* __restrict__ b1,
    const float* __restrict__ W2, const float* __restrict__ b2,
    const float* __restrict__ g, const float* __restrict__ bb_,
    float* __restrict__ h_out)
{
  __shared__ float u[256*16];
  __shared__ float hid[128*16];
  __shared__ float r[16*128];
  int t = threadIdx.x;
  int n0 = blockIdx.x * 16;
  {
    int l = t & 15, n = t >> 4;
    const float* hr = h   + (size_t)(n0+n)*128;
    const float* ar = agg + (size_t)(n0+n)*128;
    #pragma unroll
    for (int i = 0; i < 8; i++){
      int k = l + 16*i;
      u[k*16 + n]         = hr[k];
      u[(128 + k)*16 + n] = ar[k];
    }
  }
  __syncthreads();
  int c = t & 63, q = t >> 6;
  {
    float acc[8];
    #pragma unroll
    for (int i = 0; i < 8; i++) acc[i] = 0.f;
    const float4* uv = (const float4*)u;
    for (int k = 0; k < 256; k++){
      float wa = W1[k*128 + c];
      float wb = W1[k*128 + c + 64];
      float4 u4 = uv[k*4 + q];
      acc[0]+=wa*u4.x; acc[1]+=wa*u4.y; acc[2]+=wa*u4.z; acc[3]+=wa*u4.w;
      acc[4]+=wb*u4.x; acc[5]+=wb*u4.y; acc[6]+=wb*u4.z; acc[7]+=wb*u4.w;
    }
    float ba = b1[c], bv = b1[c + 64];
    #pragma unroll
    for (int i = 0; i < 4; i++){
      int n = q*4 + i;
      hid[c*16 + n]        = silu_f(acc[i] + ba);
      hid[(c+64)*16 + n]   = silu_f(acc[4+i] + bv);
    }
  }
  __syncthreads();
  {
    float acc[8];
    #pragma unroll
    for (int i = 0; i < 8; i++) acc[i] = 0.f;
    const float4* hv = (const float4*)hid;
    for (int k = 0; k < 128; k++){
      float wa = W2[k*128 + c];
      float wb = W2[k*128 + c + 64];
      float4 h4 = hv[k*4 + q];
      acc[0]+=wa*h4.x; acc[1]+=wa*h4.y; acc[2]+=wa*h4.z; acc[3]+=wa*h4.w;
      acc[4]+=wb*h4.x; acc[5]+=wb*h4.y; acc[6]+=wb*h4.z; acc[7]+=wb*h4.w;
    }
    float ba = b2[c], bv = b2[c + 64];
    #pragma unroll
    for (int i = 0; i < 4; i++){
      int n = q*4 + i;
      r[n*128 + c]      = h[(size_t)(n0+n)*128 + c]      + acc[i]   + ba;
      r[n*128 + c + 64] = h[(size_t)(n0+n)*128 + c + 64] + acc[4+i] + bv;
    }
  }
  __syncthreads();
  {
    int lane = t & 63, wid = t >> 6;
    #pragma unroll
    for (int nn = 0; nn < 4; nn++){
      int n = wid*4 + nn;
      float a = r[n*128 + lane], b2v = r[n*128 + lane + 64];
      float s = a + b2v, ss = a*a + b2v*b2v;
      #pragma unroll
      for (int off = 1; off < 64; off <<= 1){
        s  += __shfl_xor(s, off);
        ss += __shfl_xor(ss, off);
      }
      float mean = s * (1.f/128.f);
      float var  = ss * (1.f/128.f) - mean*mean;
      float rstd = rsqrtf(var + 1e-5f);
      float* ho = h_out + (size_t)(n0+n)*128;
      ho[lane]      = (a   - mean)*rstd*g[lane]      + bb_[lane];
      ho[lane + 64] = (b2v - mean)*rstd*g[lane + 64] + bb_[lane + 64];
    }
  }
}

// ---------------- output ----------------
__global__ __launch_bounds__(128) void k_out(
    const float* __restrict__ h, const float* __restrict__ vel,
    const float* __restrict__ W1, const float* __restrict__ b1,
    const float* __restrict__ W2, const float* __restrict__ b2,
    float* __restrict__ out)
{
  __shared__ float sh[128];
  __shared__ float spart[2];
  int n = blockIdx.x, t = threadIdx.x;
  sh[t] = h[(size_t)n*128 + t];
  __syncthreads();
  float acc = b1[t];
  for (int k = 0; k < 128; k++) acc += sh[k] * W1[k*128 + t];
  float p = silu_f(acc) * W2[t];
  #pragma unroll
  for (int off = 32; off; off >>= 1) p += __shfl_down(p, off);
  if ((t & 63) == 0) spart[t >> 6] = p;
  __syncthreads();
  if (t < 3){
    float scale = spart[0] + spart[1] + b2[0];
    out[n*3 + t] = vel[n*3 + t] * scale;
  }
}

extern "C" void kernel_launch(void* const* d_in, const int* in_sizes, int n_in,
                              void* d_out, int out_size, void* d_ws, size_t ws_size,
                              hipStream_t stream)
{
  const float* x_t       = (const float*)d_in[0];
  const float* t_query   = (const float*)d_in[1];
  const float* atom_pos  = (const float*)d_in[2];
  const float* atom_feat = (const float*)d_in[3];
  const int*   e_aq_s = (const int*)d_in[4];
  const int*   e_aq_t = (const int*)d_in[5];
  const int*   e_qq_s = (const int*)d_in[6];
  const int*   e_qq_t = (const int*)d_in[7];
  const float* apW  = (const float*)d_in[8];
  const float* apb  = (const float*)d_in[9];
  const float* tW1  = (const float*)d_in[10];
  const float* tb1  = (const float*)d_in[11];
  const float* tW2  = (const float*)d_in[12];
  const float* tb2  = (const float*)d_in[13];
  const float* qiW1 = (const float*)d_in[14];
  const float* qib1 = (const float*)d_in[15];
  const float* qiW2 = (const float*)d_in[16];
  const float* qib2 = (const float*)d_in[17];
  const float* mW1  = (const float*)d_in[18];
  const float* mb1  = (const float*)d_in[19];
  const float* mW2  = (const float*)d_in[20];
  const float* mb2  = (const float*)d_in[21];
  const float* cW1  = (const float*)d_in[22];
  const float* cb1  = (const float*)d_in[23];
  const float* cW2  = (const float*)d_in[24];
  const float* cb2  = (const float*)d_in[25];
  const float* nW1  = (const float*)d_in[26];
  const float* nb1  = (const float*)d_in[27];
  const float* nW2  = (const float*)d_in[28];
  const float* nb2  = (const float*)d_in[29];
  const float* lng  = (const float*)d_in[30];
  const float* lnb  = (const float*)d_in[31];
  const float* voW1 = (const float*)d_in[32];
  const float* vob1 = (const float*)d_in[33];
  const float* voW2 = (const float*)d_in[34];
  const float* vob2 = (const float*)d_in[35];
  float* out = (float*)d_out;

  float* ws     = (float*)d_ws;
  float* h_atom = ws;                       // 512*128
  float* temb   = h_atom + 65536;           // NQT*128
  float* hA     = temb + 2097152;
  float* hB     = hA + 2097152;
  float* agg    = hB + 2097152;
  float* vel    = agg + 2097152;            // NQT*3
  short* W1p    = (short*)(vel + 49152);    // 8*98304 shorts
  short* W2p    = W1p + 8*98304;            // 8*32768
  short* W3p    = W2p + 8*32768;            // 8*8192

  // weight packing (every launch — ws is re-poisoned)
  {
    int t1 = 8*16*12*512;
    k_pack<<<(t1+255)/256, 256, 0, stream>>>(mW1, W1p, 385, 256, 12, 16, t1, 1);
    int t2 = 8*8*8*512;
    k_pack<<<(t2+255)/256, 256, 0, stream>>>(mW2, W2p, 256, 128, 8, 8, t2, 0);
    int t3 = 8*4*4*512;
    k_pack<<<(t3+255)/256, 256, 0, stream>>>(cW1, W3p, 128, 64, 4, 4, t3, 0);
  }

  hipMemsetAsync(vel, 0, (size_t)NQT*3*sizeof(float), stream);
  k_hatom<<<NAT, 128, 0, stream>>>(atom_feat, apW, apb, h_atom);
  k_temb<<<NQT/8, 256, 0, stream>>>(t_query, tW1, tb1, tW2, tb2, temb);
  k_hinit<<<NQT, 128, 0, stream>>>(x_t, atom_pos, qiW1, qib1, qiW2, qib2, hA);

  float* hc = hA; float* hn = hB;
  for (int i = 0; i < 4; i++){
    for (int half = 0; half < 2; half++){
      int j = 2*i + half;
      const int* es = half ? e_qq_s : e_aq_s;
      const int* et = half ? e_qq_t : e_aq_t;
      int E = half ? EQQ : EAQ;
      const float* hsrc = half ? hc : h_atom;
      const float* psrc = half ? x_t : atom_pos;
      hipMemsetAsync(agg, 0, (size_t)NQT*128*sizeof(float), stream);
      k_edge<<<E/32, 256, 0, stream>>>(hsrc, hc, psrc, x_t, temb, es, et,
          W1p + (size_t)j*98304, mW1 + (size_t)j*385*256, mb1 + (size_t)j*256,
          W2p + (size_t)j*32768, mb2 + (size_t)j*128,
          W3p + (size_t)j*8192,  cb1 + (size_t)j*64,
          cW2 + (size_t)j*64,    cb2 + (size_t)j,
          agg, vel);
      k_node<<<NQT/16, 256, 0, stream>>>(hc, agg,
          nW1 + (size_t)j*256*128, nb1 + (size_t)j*128,
          nW2 + (size_t)j*128*128, nb2 + (size_t)j*128,
          lng + (size_t)j*128,     lnb + (size_t)j*128, hn);
      float* tmp = hc; hc = hn; hn = tmp;
    }
  }
  k_out<<<NQT, 128, 0, stream>>>(hc, vel, voW1, vob1, voW2, vob2, out);
}